// Round 10
// baseline (231.748 us; speedup 1.0000x reference)
//
#include <hip/hip_runtime.h>
#include <hip/hip_bf16.h>
#include <cstdint>

typedef __attribute__((ext_vector_type(8))) __bf16 bf8;
typedef __attribute__((ext_vector_type(4))) float f32x4;

#if defined(__has_builtin)
#if __has_builtin(__builtin_amdgcn_global_load_lds)
#define USE_GLL 1
#endif
#endif
#ifndef USE_GLL
#define USE_GLL 0
#endif

#if USE_GLL
// global src is a PER-LANE address; LDS dst is wave-uniform base,
// HW deposits lane i at dst + i*16B.
__device__ __forceinline__ void gll16(const __bf16* g, __bf16* l){
  __builtin_amdgcn_global_load_lds(
      (const __attribute__((address_space(1))) void*)g,
      (__attribute__((address_space(3))) void*)l, 16, 0, 0);
}
#endif

// order-preserving float<->uint maps (for atomicMin/Max on sim values)
__device__ __forceinline__ unsigned mapf(float x){
  unsigned u = __float_as_uint(x);
  return (u & 0x80000000u) ? ~u : (u | 0x80000000u);
}
__device__ __forceinline__ float unmapf(unsigned u){
  return __uint_as_float((u & 0x80000000u) ? (u & 0x7FFFFFFFu) : ~u);
}

__device__ float digammaf_(float x){
  float r = 0.f;
  while (x < 6.f){ r -= 1.f/x; x += 1.f; }
  float inv = 1.f/x, inv2 = inv*inv;
  r += logf(x) - 0.5f*inv
     - inv2*(0.08333333333f - inv2*(0.008333333333f - inv2*0.003968253968f));
  return r;
}

// ============ k_prep: normalize -> TILED bf16 (fb2) + per-sample losses =====
// fb2 layout (round-7 validated): panel p=row/64, chunk c=k/32, 4KB contiguous
// chunks; elem (r,kk) at (p*16+c)*2048 + r*32 + ((kk/8 ^ ((r>>1)&3))*8) + kk%8.
__global__ __launch_bounds__(256) void k_prep(const float* __restrict__ feat,
    __bf16* __restrict__ fb2,
    const float* __restrict__ logits, const int* __restrict__ targets,
    const float* __restrict__ alpha,  const float* __restrict__ fa,
    const float* __restrict__ cw, int B, int D,
    float* __restrict__ psum, unsigned* rowMinU, unsigned* rowMaxU,
    unsigned* done){
  int bid = blockIdx.x, tid = threadIdx.x;
  int wave = tid >> 6, lane = tid & 63;
  __shared__ float sloc[4][8];

  if (bid == 0 && tid == 0) *done = 0u;

  int row = bid*4 + wave;                       // grid = B/4, always < B
  // ---- normalize one row per wave ----
  const float* src = feat + (size_t)row*D;
  float ss = 0.f;
  for (int c = lane*4; c < D; c += 64*4){
    float4 v = *(const float4*)(src + c);
    ss += v.x*v.x + v.y*v.y + v.z*v.z + v.w*v.w;
  }
  #pragma unroll
  for (int off=32; off; off>>=1) ss += __shfl_xor(ss, off);
  float inv = 1.f / fmaxf(sqrtf(ss), 1e-12f);

  int p = row >> 6, r = row & 63;
  int rsw = (r >> 1) & 3;
  for (int c = lane*8; c < D; c += 64*8){
    float4 v0 = *(const float4*)(src + c);
    float4 v1 = *(const float4*)(src + c + 4);
    bf8 o;
    o[0]=(__bf16)(v0.x*inv); o[1]=(__bf16)(v0.y*inv);
    o[2]=(__bf16)(v0.z*inv); o[3]=(__bf16)(v0.w*inv);
    o[4]=(__bf16)(v1.x*inv); o[5]=(__bf16)(v1.y*inv);
    o[6]=(__bf16)(v1.z*inv); o[7]=(__bf16)(v1.w*inv);
    int cc = c >> 5;                  // chunk
    int cb = (c >> 3) & 3;            // 8-elem group within chunk
    size_t off = (size_t)(p*16 + cc)*2048 + r*32 + ((cb ^ rsw)*8);
    *(bf8*)(fb2 + off) = o;
  }

  // ---- init row min/max (4 rows per block) ----
  if (tid < 4){ rowMinU[bid*4+tid] = 0xFFFFFFFFu; rowMaxU[bid*4+tid] = 0u; }

  // ---- per-sample losses: sample i = row (redundant across lanes) ----
  int i = row;
  float l0=logits[3*i], l1=logits[3*i+1], l2=logits[3*i+2];
  int t = targets[i];
  float m = fmaxf(l0, fmaxf(l1,l2));
  float e0=expf(l0-m), e1=expf(l1-m), e2=expf(l2-m);
  float se = e0+e1+e2;
  float lse = m + logf(se);
  float lp0=l0-lse, lp1=l1-lse, lp2=l2-lse;
  float lpt = (t==0)?lp0:((t==1)?lp1:lp2);
  float nll = -lpt;
  float ce_ls = 0.9f*nll + 0.1f*(-(lp0+lp1+lp2)*(1.f/3.f));
  float pt = expf(-ce_ls);
  float om = 1.f - pt;
  float focal_i = fa[t]*om*om*ce_ls;
  float w = cw[t];
  float ce_n = w*nll, ce_d = w;
  float p0=e0/se, p1=e1/se, p2=e2/se;
  float bnd;
  if (t==0)      bnd = p1 + 0.6f*p2;
  else if (t==2) bnd = p1 + 0.4f*p0;
  else           bnd = 4.5f*(1.f - p1 + 0.3f*(p0+p2));
  float a0=alpha[3*i], a1=alpha[3*i+1], a2=alpha[3*i+2];
  float S = a0+a1+a2 + 1e-8f;
  float at_ = (t==0)?a0:((t==1)?a1:a2);
  float lik = digammaf_(S) - digammaf_(at_ + 1e-8f);
  float b0 = (t==0)?1.f:a0, b1 = (t==1)?1.f:a1, b2 = (t==2)?1.f:a2;
  float ats = b0+b1+b2 + 1e-8f;
  float psa = digammaf_(ats + 1e-8f);
  float kl = lgammaf(ats)
     - (lgammaf(b0+1e-8f)+lgammaf(b1+1e-8f)+lgammaf(b2+1e-8f))
     + (b0-1.f)*(digammaf_(b0+1e-8f)-psa)
     + (b1-1.f)*(digammaf_(b1+1e-8f)-psa)
     + (b2-1.f)*(digammaf_(b2+1e-8f)-psa);
  if (lane == 0){
    sloc[wave][0]=focal_i; sloc[wave][1]=ce_n; sloc[wave][2]=ce_d;
    sloc[wave][3]=bnd;     sloc[wave][4]=lik;  sloc[wave][5]=kl;
  }
  __syncthreads();
  if (tid < 6)
    psum[bid*8+tid] = sloc[0][tid]+sloc[1][tid]+sloc[2][tid]+sloc[3][tid];
}

// ============ k_pairs: single-wave 64x64 tiles, gll->LDS, TRIPLE buffer =====
// 2080 blocks x 64 threads, triangular (by<=bx), no barriers (single wave).
// Prefetch distance 2: gll for chunk it+2 issued while computing chunk it
// (round-7 distance-1 left ~200cyc/iter of exposed L2 latency; 2 COMPUTEs
// ~300cyc now cover the ~300-400cyc L2 latency). Fire-and-forget staging,
// cheap ds_read consume. Last-finishing block runs the finalize.
__global__ __launch_bounds__(64) void k_pairs(const __bf16* __restrict__ fb2,
    const int* __restrict__ targets, int B, int D,
    float* __restrict__ pairPart, unsigned* rowMinU, unsigned* rowMaxU,
    unsigned* done, int nblk, int nprep,
    const float* __restrict__ psum, const int* __restrict__ epoch_p,
    float* __restrict__ out){
  __shared__ __bf16 sA[3][2048];
  __shared__ __bf16 sB[3][2048];

  // decode triangular tile index -> (by, bx), by <= bx
  int t = blockIdx.x;
  int bx = (int)((sqrtf(8.f*(float)t + 1.f) - 1.f)*0.5f);
  while ((bx+1)*(bx+2)/2 <= t) bx++;
  while (bx*(bx+1)/2 > t) bx--;
  int by = t - bx*(bx+1)/2;
  bool isDiag = (by == bx);
  int rowBase = by*64, colBase = bx*64;

  int lane = threadIdx.x;
  int quad = lane >> 4, l16 = lane & 15;
  int NCH = D/32;                                   // 16 chunks per panel

  const __bf16* srcA = fb2 + (size_t)by*NCH*2048 + lane*8;  // per-lane 16B
  const __bf16* srcB = fb2 + (size_t)bx*NCH*2048 + lane*8;

  // fragment LDS offsets (elements), inverse of baked swizzle
  int offA[4];
  #pragma unroll
  for (int mi=0; mi<4; mi++){
    int R = mi*16 + l16;
    offA[mi] = R*32 + ((quad ^ ((R>>1)&3))*8);
  }

  f32x4 C[4][4] = {};

#if USE_GLL
  #define STAGE(buf, it) do{ \
    const __bf16* ga_ = srcA + (it)*2048; \
    gll16(ga_ + 0*512, &sA[buf][0*512]); \
    gll16(ga_ + 1*512, &sA[buf][1*512]); \
    gll16(ga_ + 2*512, &sA[buf][2*512]); \
    gll16(ga_ + 3*512, &sA[buf][3*512]); \
    if (!isDiag){ \
      const __bf16* gb_ = srcB + (it)*2048; \
      gll16(gb_ + 0*512, &sB[buf][0*512]); \
      gll16(gb_ + 1*512, &sB[buf][1*512]); \
      gll16(gb_ + 2*512, &sB[buf][2*512]); \
      gll16(gb_ + 3*512, &sB[buf][3*512]); \
    } \
  }while(0)
#else
  #define STAGE(buf, it) do{ \
    const __bf16* ga_ = srcA + (it)*2048; \
    _Pragma("unroll") \
    for (int j=0; j<4; j++) \
      *(bf8*)&sA[buf][j*512 + lane*8] = *(const bf8*)(ga_ + j*512); \
    if (!isDiag){ \
      const __bf16* gb_ = srcB + (it)*2048; \
      _Pragma("unroll") \
      for (int j=0; j<4; j++) \
        *(bf8*)&sB[buf][j*512 + lane*8] = *(const bf8*)(gb_ + j*512); \
    } \
  }while(0)
#endif

  #define COMPUTE(buf) do{ \
    const __bf16* bA_ = &sA[buf][0]; \
    const __bf16* bB_ = isDiag ? bA_ : &sB[buf][0]; \
    bf8 aF[4], bF[4]; \
    _Pragma("unroll") \
    for (int mi=0; mi<4; mi++) aF[mi] = *(const bf8*)(bA_ + offA[mi]); \
    _Pragma("unroll") \
    for (int ni=0; ni<4; ni++) bF[ni] = *(const bf8*)(bB_ + offA[ni]); \
    _Pragma("unroll") \
    for (int mi=0; mi<4; mi++) \
      _Pragma("unroll") \
      for (int ni=0; ni<4; ni++) \
        C[mi][ni] = __builtin_amdgcn_mfma_f32_16x16x32_bf16(aF[mi], bF[ni], C[mi][ni], 0,0,0); \
  }while(0)

  if (NCH == 16){
    STAGE(0, 0); STAGE(1, 1);
    #pragma unroll
    for (int it=0; it<16; ++it){
      if (it+2 < 16) STAGE((it+2)%3, it+2);
      COMPUTE(it%3);
    }
  } else {
    STAGE(0, 0); if (NCH > 1) STAGE(1, 1);
    for (int it=0; it<NCH; ++it){
      int nxt = (it+2)%3;
      if (it+2 < NCH) STAGE(nxt, it+2);
      COMPUTE(it%3);
    }
  }

  // ---- fused epilogue (validated rounds 1-9, absmax 0) ----
  int tcol[4];
  #pragma unroll
  for (int ni=0; ni<4; ni++) tcol[ni] = targets[colBase + ni*16 + l16];

  float pos=0.f, neg=0.f, semi=0.f, diag=0.f;
  float cmin[4], cmax[4];
  #pragma unroll
  for (int ni=0; ni<4; ni++){ cmin[ni]=2.f; cmax[ni]=-2.f; }

  #pragma unroll
  for (int mi=0; mi<4; mi++){
    #pragma unroll
    for (int r=0; r<4; r++){
      int rl = mi*16 + quad*4 + r;
      int row = rowBase + rl;
      int tr = targets[row];
      float vmin = 2.f, vmax = -2.f;
      #pragma unroll
      for (int ni=0; ni<4; ni++){
        int col = colBase + ni*16 + l16;
        float s = C[mi][ni][r];
        if (tr == tcol[ni]){
          float omv = 1.f - s;
          float q = omv*omv;
          pos += q;
          if (tr == 1) semi += q;
          if (row == col) diag += q;     // only possible on diagonal tiles
          else {
            vmin = fminf(vmin, s);
            cmin[ni] = fminf(cmin[ni], s);
          }
        } else {
          float c0 = fmaxf(s - 0.2f, 0.f);
          neg += c0*c0;
          vmax = fmaxf(vmax, s);
          cmax[ni] = fmaxf(cmax[ni], s);
        }
      }
      #pragma unroll
      for (int off=1; off<16; off<<=1){
        vmin = fminf(vmin, __shfl_xor(vmin, off));
        vmax = fmaxf(vmax, __shfl_xor(vmax, off));
      }
      if (l16 == 0){
        atomicMin(&rowMinU[row], mapf(vmin));
        atomicMax(&rowMaxU[row], mapf(vmax));
      }
    }
  }

  if (!isDiag){
    #pragma unroll
    for (int ni=0; ni<4; ni++){
      float cn = cmin[ni], cx = cmax[ni];
      cn = fminf(cn, __shfl_xor(cn, 16)); cn = fminf(cn, __shfl_xor(cn, 32));
      cx = fmaxf(cx, __shfl_xor(cx, 16)); cx = fmaxf(cx, __shfl_xor(cx, 32));
      if (quad == 0){
        int col = colBase + ni*16 + l16;
        atomicMin(&rowMinU[col], mapf(cn));
        atomicMax(&rowMaxU[col], mapf(cx));
      }
    }
  }

  #pragma unroll
  for (int off=32; off; off>>=1){
    pos  += __shfl_xor(pos, off);
    neg  += __shfl_xor(neg, off);
    semi += __shfl_xor(semi, off);
    diag += __shfl_xor(diag, off);
  }
  if (lane == 0){
    float fac = isDiag ? 1.f : 2.f;
    pairPart[blockIdx.x*4+0] = pos*fac;
    pairPart[blockIdx.x*4+1] = neg*fac;
    pairPart[blockIdx.x*4+2] = semi*fac;
    pairPart[blockIdx.x*4+3] = diag;
  }

  // ---- last-block finalize (device-scope counter handshake, validated) ----
  __threadfence();                       // release: our stores visible
  unsigned old = 0;
  if (lane == 0) old = atomicAdd(done, 1u);
  old = (unsigned)__shfl((int)old, 0);
  if (old != (unsigned)(nblk - 1)) return;
  __threadfence();                       // acquire: everyone's stores visible

  // histogram targets
  int c0=0,c1=0,c2=0;
  for (int i4 = lane; i4 < B/4; i4 += 64){
    int4 tv = ((const int4*)targets)[i4];
    c0 += (tv.x==0)+(tv.y==0)+(tv.z==0)+(tv.w==0);
    c1 += (tv.x==1)+(tv.y==1)+(tv.z==1)+(tv.w==1);
    c2 += (tv.x==2)+(tv.y==2)+(tv.z==2)+(tv.w==2);
  }
  #pragma unroll
  for (int off=32; off; off>>=1){
    c0+=__shfl_xor(c0,off); c1+=__shfl_xor(c1,off); c2+=__shfl_xor(c2,off);
  }
  int n0=c0, n1=c1, n2=c2;

  // per-sample partials
  float v0=0,v1=0,v2=0,v3=0,v4=0,v5=0;
  for (int s = lane; s < nprep; s += 64){
    float4 a = *(const float4*)(psum + s*8);
    float4 b = *(const float4*)(psum + s*8 + 4);
    v0+=a.x; v1+=a.y; v2+=a.z; v3+=a.w; v4+=b.x; v5+=b.y;
  }
  // pair partials
  float pp=0,nn=0,ss=0,dd=0;
  for (int s = lane; s < nblk; s += 64){
    float4 a = *(const float4*)(pairPart + s*4);
    pp+=a.x; nn+=a.y; ss+=a.z; dd+=a.w;
  }
  // triplet
  float tsum = 0.f, tcnt = 0.f;
  for (int i = lane; i < B; i += 64){
    int tt = targets[i];
    int nt = (tt==0)?n0:((tt==1)?n1:n2);
    if (nt - 1 > 0 && B - nt > 0){
      float mn = unmapf(rowMinU[i]);
      float mx = unmapf(rowMaxU[i]);
      float hp = sqrtf(fmaxf(2.f - 2.f*mn, 0.f));
      float hn = sqrtf(fmaxf(2.f - 2.f*mx, 0.f));
      float margin = 1.5f * ((tt==1) ? 2.5f : 1.f);
      tsum += fmaxf(hp - hn + margin, 0.f); tcnt += 1.f;
    }
  }
  #pragma unroll
  for (int off=32; off; off>>=1){
    v0+=__shfl_xor(v0,off); v1+=__shfl_xor(v1,off); v2+=__shfl_xor(v2,off);
    v3+=__shfl_xor(v3,off); v4+=__shfl_xor(v4,off); v5+=__shfl_xor(v5,off);
    pp+=__shfl_xor(pp,off); nn+=__shfl_xor(nn,off);
    ss+=__shfl_xor(ss,off); dd+=__shfl_xor(dd,off);
    tsum+=__shfl_xor(tsum,off); tcnt+=__shfl_xor(tcnt,off);
  }
  if (lane == 0){
    float triplet = (tcnt > 0.f) ? tsum / fmaxf(tcnt, 1.f) : 0.f;
    float Bf = (float)B;
    float focal = v0 / Bf;
    float ce = v1 / v2;
    float boundary = v3 / (Bf + 1e-8f);
    float contrastive = (pp + nn + 4.f*ss) / (Bf*Bf + 1e-8f);
    long long npl = ((long long)n0*(n0-1) + (long long)n1*(n1-1) + (long long)n2*(n2-1))/2;
    float qsum = (pp - dd) * 0.5f;
    float q = qsum / (float)(npl > 0 ? npl : 1);
    if (n2 > 0) q *= (1.f + 2.5f * ((float)n2 / Bf));
    float quality = (npl > 0) ? q : 0.f;
    int ep = epoch_p[0];
    float er = (float)ep / 25.f;
    float ann = fminf(1.f, er*er);
    float evidential = v4/Bf + ann*0.2f*v5/Bf;
    float total = 0.4f*focal + 0.3f*ce + 0.15f*boundary
                + 0.1f*contrastive + 0.1f*triplet + 0.1f*quality + 0.1f*evidential;
    out[0] = total;
  }
}

extern "C" void kernel_launch(void* const* d_in, const int* in_sizes, int n_in,
                              void* d_out, int out_size, void* d_ws, size_t ws_size,
                              hipStream_t stream){
  const float* logits   = (const float*)d_in[0];
  const int*   targets  = (const int*)d_in[1];
  const float* features = (const float*)d_in[2];
  const float* alpha    = (const float*)d_in[3];
  const int*   epoch    = (const int*)d_in[4];
  const float* fa       = (const float*)d_in[5];
  const float* cw       = (const float*)d_in[6];
  int B = in_sizes[1];
  int D = in_sizes[2] / B;
  int nprep = B/4;                 // k_prep blocks == psum slots
  int T  = B / 64;
  int nblk = T*(T+1)/2;            // triangular: by <= bx

  char* ws = (char*)d_ws;
  float*    psum     = (float*)(ws);                          // nprep*8 f32 (32KB)
  unsigned* done     = (unsigned*)(ws + 49152);               // 1 u32
  float*    pairPart = (float*)(ws + 65536);                  // nblk*4 f32 (~33KB)
  unsigned* rowMinU  = (unsigned*)(ws + 131072);              // B u32
  unsigned* rowMaxU  = (unsigned*)(ws + 131072 + (size_t)B*4);
  __bf16*   fb2      = (__bf16*)(ws + 131072 + (size_t)B*8);  // B*D bf16 tiled

  k_prep <<<nprep, 256, 0, stream>>>(features, fb2, logits, targets, alpha, fa, cw,
                                     B, D, psum, rowMinU, rowMaxU, done);
  k_pairs<<<nblk, 64, 0, stream>>>(fb2, targets, B, D, pairPart, rowMinU, rowMaxU,
                                   done, nblk, nprep, psum, epoch, (float*)d_out);
}

// Round 11
// 138.615 us; speedup vs baseline: 1.6719x; 1.6719x over previous
//
#include <hip/hip_runtime.h>
#include <hip/hip_bf16.h>
#include <cstdint>

typedef __attribute__((ext_vector_type(8))) __bf16 bf8;
typedef __attribute__((ext_vector_type(4))) float f32x4;

#if defined(__has_builtin)
#if __has_builtin(__builtin_amdgcn_global_load_lds)
#define USE_GLL 1
#endif
#endif
#ifndef USE_GLL
#define USE_GLL 0
#endif

#if USE_GLL
// global src is a PER-LANE address; LDS dst is wave-uniform base,
// HW deposits lane i at dst + i*16B.
__device__ __forceinline__ void gll16(const __bf16* g, __bf16* l){
  __builtin_amdgcn_global_load_lds(
      (const __attribute__((address_space(1))) void*)g,
      (__attribute__((address_space(3))) void*)l, 16, 0, 0);
}
#endif

// order-preserving float<->uint maps (for atomicMin/Max on sim values)
__device__ __forceinline__ unsigned mapf(float x){
  unsigned u = __float_as_uint(x);
  return (u & 0x80000000u) ? ~u : (u | 0x80000000u);
}
__device__ __forceinline__ float unmapf(unsigned u){
  return __uint_as_float((u & 0x80000000u) ? (u & 0x7FFFFFFFu) : ~u);
}

__device__ float digammaf_(float x){
  float r = 0.f;
  while (x < 6.f){ r -= 1.f/x; x += 1.f; }
  float inv = 1.f/x, inv2 = inv*inv;
  r += logf(x) - 0.5f*inv
     - inv2*(0.08333333333f - inv2*(0.008333333333f - inv2*0.003968253968f));
  return r;
}

// ============ k_prep: normalize -> TILED bf16 (fb2) + per-sample losses =====
// fb2 layout (round-7 validated): panel p=row/64, chunk c=k/32, 4KB contiguous
// chunks; elem (r,kk) at (p*16+c)*2048 + r*32 + ((kk/8 ^ ((r>>1)&3))*8) + kk%8.
__global__ __launch_bounds__(256) void k_prep(const float* __restrict__ feat,
    __bf16* __restrict__ fb2,
    const float* __restrict__ logits, const int* __restrict__ targets,
    const float* __restrict__ alpha,  const float* __restrict__ fa,
    const float* __restrict__ cw, int B, int D,
    float* __restrict__ psum, unsigned* rowMinU, unsigned* rowMaxU){
  int bid = blockIdx.x, tid = threadIdx.x;
  int wave = tid >> 6, lane = tid & 63;
  __shared__ float sloc[4][8];

  int row = bid*4 + wave;                       // grid = B/4, always < B
  // ---- normalize one row per wave ----
  const float* src = feat + (size_t)row*D;
  float ss = 0.f;
  for (int c = lane*4; c < D; c += 64*4){
    float4 v = *(const float4*)(src + c);
    ss += v.x*v.x + v.y*v.y + v.z*v.z + v.w*v.w;
  }
  #pragma unroll
  for (int off=32; off; off>>=1) ss += __shfl_xor(ss, off);
  float inv = 1.f / fmaxf(sqrtf(ss), 1e-12f);

  int p = row >> 6, r = row & 63;
  int rsw = (r >> 1) & 3;
  for (int c = lane*8; c < D; c += 64*8){
    float4 v0 = *(const float4*)(src + c);
    float4 v1 = *(const float4*)(src + c + 4);
    bf8 o;
    o[0]=(__bf16)(v0.x*inv); o[1]=(__bf16)(v0.y*inv);
    o[2]=(__bf16)(v0.z*inv); o[3]=(__bf16)(v0.w*inv);
    o[4]=(__bf16)(v1.x*inv); o[5]=(__bf16)(v1.y*inv);
    o[6]=(__bf16)(v1.z*inv); o[7]=(__bf16)(v1.w*inv);
    int cc = c >> 5;                  // chunk
    int cb = (c >> 3) & 3;            // 8-elem group within chunk
    size_t off = (size_t)(p*16 + cc)*2048 + r*32 + ((cb ^ rsw)*8);
    *(bf8*)(fb2 + off) = o;
  }

  // ---- init row min/max (4 rows per block) ----
  if (tid < 4){ rowMinU[bid*4+tid] = 0xFFFFFFFFu; rowMaxU[bid*4+tid] = 0u; }

  // ---- per-sample losses: sample i = row (redundant across lanes) ----
  int i = row;
  float l0=logits[3*i], l1=logits[3*i+1], l2=logits[3*i+2];
  int t = targets[i];
  float m = fmaxf(l0, fmaxf(l1,l2));
  float e0=expf(l0-m), e1=expf(l1-m), e2=expf(l2-m);
  float se = e0+e1+e2;
  float lse = m + logf(se);
  float lp0=l0-lse, lp1=l1-lse, lp2=l2-lse;
  float lpt = (t==0)?lp0:((t==1)?lp1:lp2);
  float nll = -lpt;
  float ce_ls = 0.9f*nll + 0.1f*(-(lp0+lp1+lp2)*(1.f/3.f));
  float pt = expf(-ce_ls);
  float om = 1.f - pt;
  float focal_i = fa[t]*om*om*ce_ls;
  float w = cw[t];
  float ce_n = w*nll, ce_d = w;
  float p0=e0/se, p1=e1/se, p2=e2/se;
  float bnd;
  if (t==0)      bnd = p1 + 0.6f*p2;
  else if (t==2) bnd = p1 + 0.4f*p0;
  else           bnd = 4.5f*(1.f - p1 + 0.3f*(p0+p2));
  float a0=alpha[3*i], a1=alpha[3*i+1], a2=alpha[3*i+2];
  float S = a0+a1+a2 + 1e-8f;
  float at_ = (t==0)?a0:((t==1)?a1:a2);
  float lik = digammaf_(S) - digammaf_(at_ + 1e-8f);
  float b0 = (t==0)?1.f:a0, b1 = (t==1)?1.f:a1, b2 = (t==2)?1.f:a2;
  float ats = b0+b1+b2 + 1e-8f;
  float psa = digammaf_(ats + 1e-8f);
  float kl = lgammaf(ats)
     - (lgammaf(b0+1e-8f)+lgammaf(b1+1e-8f)+lgammaf(b2+1e-8f))
     + (b0-1.f)*(digammaf_(b0+1e-8f)-psa)
     + (b1-1.f)*(digammaf_(b1+1e-8f)-psa)
     + (b2-1.f)*(digammaf_(b2+1e-8f)-psa);
  if (lane == 0){
    sloc[wave][0]=focal_i; sloc[wave][1]=ce_n; sloc[wave][2]=ce_d;
    sloc[wave][3]=bnd;     sloc[wave][4]=lik;  sloc[wave][5]=kl;
  }
  __syncthreads();
  if (tid < 6)
    psum[bid*8+tid] = sloc[0][tid]+sloc[1][tid]+sloc[2][tid]+sloc[3][tid];
}

// ============ k_pairs: single-wave 64x64 tiles, gll->LDS, TRIPLE buffer =====
// 2080 blocks x 64 threads, triangular (by<=bx), no barriers, NO threadfence
// (rounds 8-10 lesson: per-block device fences wb/inv the XCD L2 and destroy
// fb2 residency for all neighbors -- finalize lives in its own kernel).
// Prefetch distance 2: gll for chunk it+2 issued before computing chunk it.
__global__ __launch_bounds__(64) void k_pairs(const __bf16* __restrict__ fb2,
    const int* __restrict__ targets, int B, int D,
    float* __restrict__ pairPart, unsigned* rowMinU, unsigned* rowMaxU){
  __shared__ __bf16 sA[3][2048];
  __shared__ __bf16 sB[3][2048];

  // decode triangular tile index -> (by, bx), by <= bx
  int t = blockIdx.x;
  int bx = (int)((sqrtf(8.f*(float)t + 1.f) - 1.f)*0.5f);
  while ((bx+1)*(bx+2)/2 <= t) bx++;
  while (bx*(bx+1)/2 > t) bx--;
  int by = t - bx*(bx+1)/2;
  bool isDiag = (by == bx);
  int rowBase = by*64, colBase = bx*64;

  int lane = threadIdx.x;
  int quad = lane >> 4, l16 = lane & 15;
  int NCH = D/32;                                   // 16 chunks per panel

  const __bf16* srcA = fb2 + (size_t)by*NCH*2048 + lane*8;  // per-lane 16B
  const __bf16* srcB = fb2 + (size_t)bx*NCH*2048 + lane*8;

  // fragment LDS offsets (elements), inverse of baked swizzle
  int offA[4];
  #pragma unroll
  for (int mi=0; mi<4; mi++){
    int R = mi*16 + l16;
    offA[mi] = R*32 + ((quad ^ ((R>>1)&3))*8);
  }

  f32x4 C[4][4] = {};

#if USE_GLL
  #define STAGE(buf, it) do{ \
    const __bf16* ga_ = srcA + (it)*2048; \
    gll16(ga_ + 0*512, &sA[buf][0*512]); \
    gll16(ga_ + 1*512, &sA[buf][1*512]); \
    gll16(ga_ + 2*512, &sA[buf][2*512]); \
    gll16(ga_ + 3*512, &sA[buf][3*512]); \
    if (!isDiag){ \
      const __bf16* gb_ = srcB + (it)*2048; \
      gll16(gb_ + 0*512, &sB[buf][0*512]); \
      gll16(gb_ + 1*512, &sB[buf][1*512]); \
      gll16(gb_ + 2*512, &sB[buf][2*512]); \
      gll16(gb_ + 3*512, &sB[buf][3*512]); \
    } \
  }while(0)
#else
  #define STAGE(buf, it) do{ \
    const __bf16* ga_ = srcA + (it)*2048; \
    _Pragma("unroll") \
    for (int j=0; j<4; j++) \
      *(bf8*)&sA[buf][j*512 + lane*8] = *(const bf8*)(ga_ + j*512); \
    if (!isDiag){ \
      const __bf16* gb_ = srcB + (it)*2048; \
      _Pragma("unroll") \
      for (int j=0; j<4; j++) \
        *(bf8*)&sB[buf][j*512 + lane*8] = *(const bf8*)(gb_ + j*512); \
    } \
  }while(0)
#endif

  #define COMPUTE(buf) do{ \
    const __bf16* bA_ = &sA[buf][0]; \
    const __bf16* bB_ = isDiag ? bA_ : &sB[buf][0]; \
    bf8 aF[4], bF[4]; \
    _Pragma("unroll") \
    for (int mi=0; mi<4; mi++) aF[mi] = *(const bf8*)(bA_ + offA[mi]); \
    _Pragma("unroll") \
    for (int ni=0; ni<4; ni++) bF[ni] = *(const bf8*)(bB_ + offA[ni]); \
    _Pragma("unroll") \
    for (int mi=0; mi<4; mi++) \
      _Pragma("unroll") \
      for (int ni=0; ni<4; ni++) \
        C[mi][ni] = __builtin_amdgcn_mfma_f32_16x16x32_bf16(aF[mi], bF[ni], C[mi][ni], 0,0,0); \
  }while(0)

  STAGE(0, 0); STAGE(1, 1);
  #pragma unroll
  for (int it=0; it<16; ++it){
    if (it+2 < 16) STAGE((it+2)%3, it+2);
    COMPUTE(it%3);
  }

  // ---- fused epilogue (validated rounds 1-10, absmax 0) ----
  int tcol[4];
  #pragma unroll
  for (int ni=0; ni<4; ni++) tcol[ni] = targets[colBase + ni*16 + l16];

  float pos=0.f, neg=0.f, semi=0.f, diag=0.f;
  float cmin[4], cmax[4];
  #pragma unroll
  for (int ni=0; ni<4; ni++){ cmin[ni]=2.f; cmax[ni]=-2.f; }

  #pragma unroll
  for (int mi=0; mi<4; mi++){
    #pragma unroll
    for (int r=0; r<4; r++){
      int rl = mi*16 + quad*4 + r;
      int row = rowBase + rl;
      int tr = targets[row];
      float vmin = 2.f, vmax = -2.f;
      #pragma unroll
      for (int ni=0; ni<4; ni++){
        int col = colBase + ni*16 + l16;
        float s = C[mi][ni][r];
        if (tr == tcol[ni]){
          float omv = 1.f - s;
          float q = omv*omv;
          pos += q;
          if (tr == 1) semi += q;
          if (row == col) diag += q;     // only possible on diagonal tiles
          else {
            vmin = fminf(vmin, s);
            cmin[ni] = fminf(cmin[ni], s);
          }
        } else {
          float c0 = fmaxf(s - 0.2f, 0.f);
          neg += c0*c0;
          vmax = fmaxf(vmax, s);
          cmax[ni] = fmaxf(cmax[ni], s);
        }
      }
      #pragma unroll
      for (int off=1; off<16; off<<=1){
        vmin = fminf(vmin, __shfl_xor(vmin, off));
        vmax = fmaxf(vmax, __shfl_xor(vmax, off));
      }
      if (l16 == 0){
        atomicMin(&rowMinU[row], mapf(vmin));
        atomicMax(&rowMaxU[row], mapf(vmax));
      }
    }
  }

  if (!isDiag){
    #pragma unroll
    for (int ni=0; ni<4; ni++){
      float cn = cmin[ni], cx = cmax[ni];
      cn = fminf(cn, __shfl_xor(cn, 16)); cn = fminf(cn, __shfl_xor(cn, 32));
      cx = fmaxf(cx, __shfl_xor(cx, 16)); cx = fmaxf(cx, __shfl_xor(cx, 32));
      if (quad == 0){
        int col = colBase + ni*16 + l16;
        atomicMin(&rowMinU[col], mapf(cn));
        atomicMax(&rowMaxU[col], mapf(cx));
      }
    }
  }

  #pragma unroll
  for (int off=32; off; off>>=1){
    pos  += __shfl_xor(pos, off);
    neg  += __shfl_xor(neg, off);
    semi += __shfl_xor(semi, off);
    diag += __shfl_xor(diag, off);
  }
  if (lane == 0){
    float fac = isDiag ? 1.f : 2.f;
    pairPart[blockIdx.x*4+0] = pos*fac;
    pairPart[blockIdx.x*4+1] = neg*fac;
    pairPart[blockIdx.x*4+2] = semi*fac;
    pairPart[blockIdx.x*4+3] = diag;
  }
}

// ============ k_final: 1024 threads; histogram + reductions + combine ======
__global__ __launch_bounds__(1024) void k_final(const int* __restrict__ targets,
    const int* __restrict__ epoch_p, int B, int nprep, int nblk,
    const float* __restrict__ pairPart, const float* __restrict__ psum,
    const unsigned* rowMinU, const unsigned* rowMaxU, float* out){
  int tid = threadIdx.x, wave = tid>>6, lane = tid&63;
  __shared__ float redf[16][8];
  __shared__ int   redi[16][4];
  __shared__ float tot6[6];
  __shared__ int   cns[3];
  __shared__ float ptot[4];

  // ---- 1) histogram targets (int4 loads) ----
  {
    int c0=0,c1=0,c2=0;
    for (int i4 = tid; i4 < B/4; i4 += 1024){
      int4 tv = ((const int4*)targets)[i4];
      c0 += (tv.x==0)+(tv.y==0)+(tv.z==0)+(tv.w==0);
      c1 += (tv.x==1)+(tv.y==1)+(tv.z==1)+(tv.w==1);
      c2 += (tv.x==2)+(tv.y==2)+(tv.z==2)+(tv.w==2);
    }
    #pragma unroll
    for (int off=32; off; off>>=1){
      c0+=__shfl_xor(c0,off); c1+=__shfl_xor(c1,off); c2+=__shfl_xor(c2,off);
    }
    if (lane==0){ redi[wave][0]=c0; redi[wave][1]=c1; redi[wave][2]=c2; }
  }
  // ---- 2) per-sample partials ----
  {
    float v0=0,v1=0,v2=0,v3=0,v4=0,v5=0;
    for (int s = tid; s < nprep; s += 1024){
      float4 a = *(const float4*)(psum + s*8);
      float4 b = *(const float4*)(psum + s*8 + 4);
      v0+=a.x; v1+=a.y; v2+=a.z; v3+=a.w; v4+=b.x; v5+=b.y;
    }
    #pragma unroll
    for (int off=32; off; off>>=1){
      v0+=__shfl_xor(v0,off); v1+=__shfl_xor(v1,off); v2+=__shfl_xor(v2,off);
      v3+=__shfl_xor(v3,off); v4+=__shfl_xor(v4,off); v5+=__shfl_xor(v5,off);
    }
    if (lane==0){
      redf[wave][0]=v0; redf[wave][1]=v1; redf[wave][2]=v2;
      redf[wave][3]=v3; redf[wave][4]=v4; redf[wave][5]=v5;
    }
  }
  __syncthreads();
  if (tid == 0){
    int c0=0,c1=0,c2=0;
    float v[6]={0,0,0,0,0,0};
    for (int w2=0; w2<16; w2++){
      c0+=redi[w2][0]; c1+=redi[w2][1]; c2+=redi[w2][2];
      for (int j=0;j<6;j++) v[j]+=redf[w2][j];
    }
    cns[0]=c0; cns[1]=c1; cns[2]=c2;
    for (int j=0;j<6;j++) tot6[j]=v[j];
  }
  __syncthreads();

  // ---- 3) pair partials ----
  {
    float p=0,n=0,s2=0,d=0;
    for (int s = tid; s < nblk; s += 1024){
      float4 a = *(const float4*)(pairPart + s*4);
      p+=a.x; n+=a.y; s2+=a.z; d+=a.w;
    }
    #pragma unroll
    for (int off=32; off; off>>=1){
      p+=__shfl_xor(p,off); n+=__shfl_xor(n,off);
      s2+=__shfl_xor(s2,off); d+=__shfl_xor(d,off);
    }
    if (lane==0){ redf[wave][0]=p; redf[wave][1]=n; redf[wave][2]=s2; redf[wave][3]=d; }
  }
  __syncthreads();
  if (tid == 0){
    float a=0,b=0,c=0,e=0;
    for (int w2=0; w2<16; w2++){ a+=redf[w2][0]; b+=redf[w2][1]; c+=redf[w2][2]; e+=redf[w2][3]; }
    ptot[0]=a; ptot[1]=b; ptot[2]=c; ptot[3]=e;
  }
  __syncthreads();

  int n0=cns[0], n1=cns[1], n2=cns[2];

  // ---- 4) triplet ----
  float tsum = 0.f, tcnt = 0.f;
  for (int i = tid; i < B; i += 1024){
    int t = targets[i];
    int nt = (t==0)?n0:((t==1)?n1:n2);
    if (nt - 1 > 0 && B - nt > 0){
      float mn = unmapf(rowMinU[i]);
      float mx = unmapf(rowMaxU[i]);
      float hp = sqrtf(fmaxf(2.f - 2.f*mn, 0.f));
      float hn = sqrtf(fmaxf(2.f - 2.f*mx, 0.f));
      float margin = 1.5f * ((t==1) ? 2.5f : 1.f);
      float tl = fmaxf(hp - hn + margin, 0.f);
      tsum += tl; tcnt += 1.f;
    }
  }
  #pragma unroll
  for (int off=32; off; off>>=1){ tsum += __shfl_xor(tsum, off); tcnt += __shfl_xor(tcnt, off); }
  if (lane==0){ redf[wave][6]=tsum; redf[wave][7]=tcnt; }
  __syncthreads();

  if (tid==0){
    float ts=0, tn=0;
    for (int w2=0; w2<16; w2++){ ts+=redf[w2][6]; tn+=redf[w2][7]; }
    float triplet = (tn > 0.f) ? ts / fmaxf(tn, 1.f) : 0.f;
    float pos=ptot[0], neg=ptot[1], semi=ptot[2], diag=ptot[3];
    float Bf = (float)B;
    float focal = tot6[0] / Bf;
    float ce = tot6[1] / tot6[2];
    float boundary = tot6[3] / (Bf + 1e-8f);
    float contrastive = (pos + neg + 4.f*semi) / (Bf*Bf + 1e-8f);
    long long npl = ((long long)n0*(n0-1) + (long long)n1*(n1-1) + (long long)n2*(n2-1))/2;
    float qsum = (pos - diag) * 0.5f;
    float q = qsum / (float)(npl > 0 ? npl : 1);
    if (n2 > 0) q *= (1.f + 2.5f * ((float)n2 / Bf));
    float quality = (npl > 0) ? q : 0.f;
    int ep = epoch_p[0];
    float er = (float)ep / 25.f;
    float ann = fminf(1.f, er*er);
    float evidential = tot6[4]/Bf + ann*0.2f*tot6[5]/Bf;
    float total = 0.4f*focal + 0.3f*ce + 0.15f*boundary
                + 0.1f*contrastive + 0.1f*triplet + 0.1f*quality + 0.1f*evidential;
    out[0] = total;
  }
}

extern "C" void kernel_launch(void* const* d_in, const int* in_sizes, int n_in,
                              void* d_out, int out_size, void* d_ws, size_t ws_size,
                              hipStream_t stream){
  const float* logits   = (const float*)d_in[0];
  const int*   targets  = (const int*)d_in[1];
  const float* features = (const float*)d_in[2];
  const float* alpha    = (const float*)d_in[3];
  const int*   epoch    = (const int*)d_in[4];
  const float* fa       = (const float*)d_in[5];
  const float* cw       = (const float*)d_in[6];
  int B = in_sizes[1];
  int D = in_sizes[2] / B;
  int nprep = B/4;                 // k_prep blocks == psum slots
  int T  = B / 64;
  int nblk = T*(T+1)/2;            // triangular: by <= bx

  char* ws = (char*)d_ws;
  float*    psum     = (float*)(ws);                          // nprep*8 f32 (32KB)
  float*    pairPart = (float*)(ws + 65536);                  // nblk*4 f32 (~33KB)
  unsigned* rowMinU  = (unsigned*)(ws + 131072);              // B u32
  unsigned* rowMaxU  = (unsigned*)(ws + 131072 + (size_t)B*4);
  __bf16*   fb2      = (__bf16*)(ws + 131072 + (size_t)B*8);  // B*D bf16 tiled

  k_prep <<<nprep, 256, 0, stream>>>(features, fb2, logits, targets, alpha, fa, cw,
                                     B, D, psum, rowMinU, rowMaxU);
  k_pairs<<<nblk, 64, 0, stream>>>(fb2, targets, B, D, pairPart, rowMinU, rowMaxU);
  k_final<<<1, 1024, 0, stream>>>(targets, epoch, B, nprep, nblk, pairPart, psum,
                                  rowMinU, rowMaxU, (float*)d_out);
}

// Round 12
// 120.724 us; speedup vs baseline: 1.9197x; 1.1482x over previous
//
#include <hip/hip_runtime.h>
#include <hip/hip_bf16.h>
#include <cstdint>

typedef __attribute__((ext_vector_type(8))) __bf16 bf8;
typedef __attribute__((ext_vector_type(4))) float f32x4;

#if defined(__has_builtin)
#if __has_builtin(__builtin_amdgcn_global_load_lds)
#define USE_GLL 1
#endif
#endif
#ifndef USE_GLL
#define USE_GLL 0
#endif

#if USE_GLL
// global src is a PER-LANE address; LDS dst is wave-uniform base,
// HW deposits lane i at dst + i*16B.
__device__ __forceinline__ void gll16(const __bf16* g, __bf16* l){
  __builtin_amdgcn_global_load_lds(
      (const __attribute__((address_space(1))) void*)g,
      (__attribute__((address_space(3))) void*)l, 16, 0, 0);
}
#endif

// order-preserving float<->uint maps (for atomicMin/Max on sim values)
__device__ __forceinline__ unsigned mapf(float x){
  unsigned u = __float_as_uint(x);
  return (u & 0x80000000u) ? ~u : (u | 0x80000000u);
}
__device__ __forceinline__ float unmapf(unsigned u){
  return __uint_as_float((u & 0x80000000u) ? (u & 0x7FFFFFFFu) : ~u);
}

__device__ float digammaf_(float x){
  float r = 0.f;
  while (x < 6.f){ r -= 1.f/x; x += 1.f; }
  float inv = 1.f/x, inv2 = inv*inv;
  r += logf(x) - 0.5f*inv
     - inv2*(0.08333333333f - inv2*(0.008333333333f - inv2*0.003968253968f));
  return r;
}

// ============ k_prep: normalize -> TILED bf16 (fb2) + per-sample losses =====
// fb2 layout (round-7 validated): panel p=row/64, chunk c=k/32, 4KB contiguous
// chunks; elem (r,kk) at (p*16+c)*2048 + r*32 + ((kk/8 ^ ((r>>1)&3))*8) + kk%8.
__global__ __launch_bounds__(256) void k_prep(const float* __restrict__ feat,
    __bf16* __restrict__ fb2,
    const float* __restrict__ logits, const int* __restrict__ targets,
    const float* __restrict__ alpha,  const float* __restrict__ fa,
    const float* __restrict__ cw, int B, int D,
    float* __restrict__ psum, unsigned* rowMinU, unsigned* rowMaxU){
  int bid = blockIdx.x, tid = threadIdx.x;
  int wave = tid >> 6, lane = tid & 63;
  __shared__ float sloc[4][8];

  int row = bid*4 + wave;                       // grid = B/4, always < B
  // ---- normalize one row per wave ----
  const float* src = feat + (size_t)row*D;
  float ss = 0.f;
  for (int c = lane*4; c < D; c += 64*4){
    float4 v = *(const float4*)(src + c);
    ss += v.x*v.x + v.y*v.y + v.z*v.z + v.w*v.w;
  }
  #pragma unroll
  for (int off=32; off; off>>=1) ss += __shfl_xor(ss, off);
  float inv = 1.f / fmaxf(sqrtf(ss), 1e-12f);

  int p = row >> 6, r = row & 63;
  int rsw = (r >> 1) & 3;
  for (int c = lane*8; c < D; c += 64*8){
    float4 v0 = *(const float4*)(src + c);
    float4 v1 = *(const float4*)(src + c + 4);
    bf8 o;
    o[0]=(__bf16)(v0.x*inv); o[1]=(__bf16)(v0.y*inv);
    o[2]=(__bf16)(v0.z*inv); o[3]=(__bf16)(v0.w*inv);
    o[4]=(__bf16)(v1.x*inv); o[5]=(__bf16)(v1.y*inv);
    o[6]=(__bf16)(v1.z*inv); o[7]=(__bf16)(v1.w*inv);
    int cc = c >> 5;                  // chunk
    int cb = (c >> 3) & 3;            // 8-elem group within chunk
    size_t off = (size_t)(p*16 + cc)*2048 + r*32 + ((cb ^ rsw)*8);
    *(bf8*)(fb2 + off) = o;
  }

  // ---- init row min/max (4 rows per block) ----
  if (tid < 4){ rowMinU[bid*4+tid] = 0xFFFFFFFFu; rowMaxU[bid*4+tid] = 0u; }

  // ---- per-sample losses: sample i = row (redundant across lanes) ----
  int i = row;
  float l0=logits[3*i], l1=logits[3*i+1], l2=logits[3*i+2];
  int t = targets[i];
  float m = fmaxf(l0, fmaxf(l1,l2));
  float e0=expf(l0-m), e1=expf(l1-m), e2=expf(l2-m);
  float se = e0+e1+e2;
  float lse = m + logf(se);
  float lp0=l0-lse, lp1=l1-lse, lp2=l2-lse;
  float lpt = (t==0)?lp0:((t==1)?lp1:lp2);
  float nll = -lpt;
  float ce_ls = 0.9f*nll + 0.1f*(-(lp0+lp1+lp2)*(1.f/3.f));
  float pt = expf(-ce_ls);
  float om = 1.f - pt;
  float focal_i = fa[t]*om*om*ce_ls;
  float w = cw[t];
  float ce_n = w*nll, ce_d = w;
  float p0=e0/se, p1=e1/se, p2=e2/se;
  float bnd;
  if (t==0)      bnd = p1 + 0.6f*p2;
  else if (t==2) bnd = p1 + 0.4f*p0;
  else           bnd = 4.5f*(1.f - p1 + 0.3f*(p0+p2));
  float a0=alpha[3*i], a1=alpha[3*i+1], a2=alpha[3*i+2];
  float S = a0+a1+a2 + 1e-8f;
  float at_ = (t==0)?a0:((t==1)?a1:a2);
  float lik = digammaf_(S) - digammaf_(at_ + 1e-8f);
  float b0 = (t==0)?1.f:a0, b1 = (t==1)?1.f:a1, b2 = (t==2)?1.f:a2;
  float ats = b0+b1+b2 + 1e-8f;
  float psa = digammaf_(ats + 1e-8f);
  float kl = lgammaf(ats)
     - (lgammaf(b0+1e-8f)+lgammaf(b1+1e-8f)+lgammaf(b2+1e-8f))
     + (b0-1.f)*(digammaf_(b0+1e-8f)-psa)
     + (b1-1.f)*(digammaf_(b1+1e-8f)-psa)
     + (b2-1.f)*(digammaf_(b2+1e-8f)-psa);
  if (lane == 0){
    sloc[wave][0]=focal_i; sloc[wave][1]=ce_n; sloc[wave][2]=ce_d;
    sloc[wave][3]=bnd;     sloc[wave][4]=lik;  sloc[wave][5]=kl;
  }
  __syncthreads();
  if (tid < 6)
    psum[bid*8+tid] = sloc[0][tid]+sloc[1][tid]+sloc[2][tid]+sloc[3][tid];
}

// ============ k_pairs: single-wave 64x64 tiles, XCD-LOCAL tile ordering =====
// 2080 blocks x 64 threads, no barriers, no fences. blockIdx is remapped so
// each XCD (blockIdx % 8, HW round-robin heuristic) gets a CONTIGUOUS arc of
// the column-major triangle -> its panel working set (~1.5-4 MB) fits its own
// 4 MB L2 instead of all 8 XCDs thrashing the full fb2 through L3 (round-11
// diagnosis: 266 MB panel re-reads served by L3 = the invariant ~45 us floor).
// Double-buffered LDS (16 KB -> 10 blocks/CU), distance-1 gll prefetch.
__global__ __launch_bounds__(64) void k_pairs(const __bf16* __restrict__ fb2,
    const int* __restrict__ targets, int B, int D,
    float* __restrict__ pairPart, unsigned* rowMinU, unsigned* rowMaxU,
    int nblk, int nper){
  __shared__ __bf16 sA[2][2048];
  __shared__ __bf16 sB[2][2048];

  // XCD-local linear tile index
  int L = (blockIdx.x & 7) * nper + (blockIdx.x >> 3);
  if (L >= nblk) return;

  // decode triangular tile index -> (by, bx), by <= bx
  int bx = (int)((sqrtf(8.f*(float)L + 1.f) - 1.f)*0.5f);
  while ((bx+1)*(bx+2)/2 <= L) bx++;
  while (bx*(bx+1)/2 > L) bx--;
  int by = L - bx*(bx+1)/2;
  bool isDiag = (by == bx);
  int rowBase = by*64, colBase = bx*64;

  int lane = threadIdx.x;
  int quad = lane >> 4, l16 = lane & 15;
  int NCH = D/32;                                   // 16 chunks per panel

  const __bf16* srcA = fb2 + (size_t)by*NCH*2048 + lane*8;  // per-lane 16B
  const __bf16* srcB = fb2 + (size_t)bx*NCH*2048 + lane*8;

  // fragment LDS offsets (elements), inverse of baked swizzle
  int offA[4];
  #pragma unroll
  for (int mi=0; mi<4; mi++){
    int R = mi*16 + l16;
    offA[mi] = R*32 + ((quad ^ ((R>>1)&3))*8);
  }

  f32x4 C[4][4] = {};

#if USE_GLL
  #define STAGE(buf, it) do{ \
    const __bf16* ga_ = srcA + (it)*2048; \
    gll16(ga_ + 0*512, &sA[buf][0*512]); \
    gll16(ga_ + 1*512, &sA[buf][1*512]); \
    gll16(ga_ + 2*512, &sA[buf][2*512]); \
    gll16(ga_ + 3*512, &sA[buf][3*512]); \
    if (!isDiag){ \
      const __bf16* gb_ = srcB + (it)*2048; \
      gll16(gb_ + 0*512, &sB[buf][0*512]); \
      gll16(gb_ + 1*512, &sB[buf][1*512]); \
      gll16(gb_ + 2*512, &sB[buf][2*512]); \
      gll16(gb_ + 3*512, &sB[buf][3*512]); \
    } \
  }while(0)
#else
  #define STAGE(buf, it) do{ \
    const __bf16* ga_ = srcA + (it)*2048; \
    _Pragma("unroll") \
    for (int j=0; j<4; j++) \
      *(bf8*)&sA[buf][j*512 + lane*8] = *(const bf8*)(ga_ + j*512); \
    if (!isDiag){ \
      const __bf16* gb_ = srcB + (it)*2048; \
      _Pragma("unroll") \
      for (int j=0; j<4; j++) \
        *(bf8*)&sB[buf][j*512 + lane*8] = *(const bf8*)(gb_ + j*512); \
    } \
  }while(0)
#endif

  #define COMPUTE(buf) do{ \
    const __bf16* bA_ = &sA[buf][0]; \
    const __bf16* bB_ = isDiag ? bA_ : &sB[buf][0]; \
    bf8 aF[4], bF[4]; \
    _Pragma("unroll") \
    for (int mi=0; mi<4; mi++) aF[mi] = *(const bf8*)(bA_ + offA[mi]); \
    _Pragma("unroll") \
    for (int ni=0; ni<4; ni++) bF[ni] = *(const bf8*)(bB_ + offA[ni]); \
    _Pragma("unroll") \
    for (int mi=0; mi<4; mi++) \
      _Pragma("unroll") \
      for (int ni=0; ni<4; ni++) \
        C[mi][ni] = __builtin_amdgcn_mfma_f32_16x16x32_bf16(aF[mi], bF[ni], C[mi][ni], 0,0,0); \
  }while(0)

  STAGE(0, 0);
  for (int it=0; it<NCH; it+=2){
    STAGE(1, it+1);
    COMPUTE(0);
    if (it+2 < NCH) STAGE(0, it+2);
    COMPUTE(1);
  }

  // ---- fused epilogue (validated rounds 1-11, absmax 0) ----
  int tcol[4];
  #pragma unroll
  for (int ni=0; ni<4; ni++) tcol[ni] = targets[colBase + ni*16 + l16];

  float pos=0.f, neg=0.f, semi=0.f, diag=0.f;
  float cmin[4], cmax[4];
  #pragma unroll
  for (int ni=0; ni<4; ni++){ cmin[ni]=2.f; cmax[ni]=-2.f; }

  #pragma unroll
  for (int mi=0; mi<4; mi++){
    #pragma unroll
    for (int r=0; r<4; r++){
      int rl = mi*16 + quad*4 + r;
      int row = rowBase + rl;
      int tr = targets[row];
      float vmin = 2.f, vmax = -2.f;
      #pragma unroll
      for (int ni=0; ni<4; ni++){
        int col = colBase + ni*16 + l16;
        float s = C[mi][ni][r];
        if (tr == tcol[ni]){
          float omv = 1.f - s;
          float q = omv*omv;
          pos += q;
          if (tr == 1) semi += q;
          if (row == col) diag += q;     // only possible on diagonal tiles
          else {
            vmin = fminf(vmin, s);
            cmin[ni] = fminf(cmin[ni], s);
          }
        } else {
          float c0 = fmaxf(s - 0.2f, 0.f);
          neg += c0*c0;
          vmax = fmaxf(vmax, s);
          cmax[ni] = fmaxf(cmax[ni], s);
        }
      }
      #pragma unroll
      for (int off=1; off<16; off<<=1){
        vmin = fminf(vmin, __shfl_xor(vmin, off));
        vmax = fmaxf(vmax, __shfl_xor(vmax, off));
      }
      if (l16 == 0){
        atomicMin(&rowMinU[row], mapf(vmin));
        atomicMax(&rowMaxU[row], mapf(vmax));
      }
    }
  }

  if (!isDiag){
    #pragma unroll
    for (int ni=0; ni<4; ni++){
      float cn = cmin[ni], cx = cmax[ni];
      cn = fminf(cn, __shfl_xor(cn, 16)); cn = fminf(cn, __shfl_xor(cn, 32));
      cx = fmaxf(cx, __shfl_xor(cx, 16)); cx = fmaxf(cx, __shfl_xor(cx, 32));
      if (quad == 0){
        int col = colBase + ni*16 + l16;
        atomicMin(&rowMinU[col], mapf(cn));
        atomicMax(&rowMaxU[col], mapf(cx));
      }
    }
  }

  #pragma unroll
  for (int off=32; off; off>>=1){
    pos  += __shfl_xor(pos, off);
    neg  += __shfl_xor(neg, off);
    semi += __shfl_xor(semi, off);
    diag += __shfl_xor(diag, off);
  }
  if (lane == 0){
    float fac = isDiag ? 1.f : 2.f;
    pairPart[L*4+0] = pos*fac;
    pairPart[L*4+1] = neg*fac;
    pairPart[L*4+2] = semi*fac;
    pairPart[L*4+3] = diag;
  }
}

// ============ k_final: 1024 threads; histogram + reductions + combine ======
__global__ __launch_bounds__(1024) void k_final(const int* __restrict__ targets,
    const int* __restrict__ epoch_p, int B, int nprep, int nblk,
    const float* __restrict__ pairPart, const float* __restrict__ psum,
    const unsigned* rowMinU, const unsigned* rowMaxU, float* out){
  int tid = threadIdx.x, wave = tid>>6, lane = tid&63;
  __shared__ float redf[16][8];
  __shared__ int   redi[16][4];
  __shared__ float tot6[6];
  __shared__ int   cns[3];
  __shared__ float ptot[4];

  // ---- 1) histogram targets (int4 loads) ----
  {
    int c0=0,c1=0,c2=0;
    for (int i4 = tid; i4 < B/4; i4 += 1024){
      int4 tv = ((const int4*)targets)[i4];
      c0 += (tv.x==0)+(tv.y==0)+(tv.z==0)+(tv.w==0);
      c1 += (tv.x==1)+(tv.y==1)+(tv.z==1)+(tv.w==1);
      c2 += (tv.x==2)+(tv.y==2)+(tv.z==2)+(tv.w==2);
    }
    #pragma unroll
    for (int off=32; off; off>>=1){
      c0+=__shfl_xor(c0,off); c1+=__shfl_xor(c1,off); c2+=__shfl_xor(c2,off);
    }
    if (lane==0){ redi[wave][0]=c0; redi[wave][1]=c1; redi[wave][2]=c2; }
  }
  // ---- 2) per-sample partials ----
  {
    float v0=0,v1=0,v2=0,v3=0,v4=0,v5=0;
    for (int s = tid; s < nprep; s += 1024){
      float4 a = *(const float4*)(psum + s*8);
      float4 b = *(const float4*)(psum + s*8 + 4);
      v0+=a.x; v1+=a.y; v2+=a.z; v3+=a.w; v4+=b.x; v5+=b.y;
    }
    #pragma unroll
    for (int off=32; off; off>>=1){
      v0+=__shfl_xor(v0,off); v1+=__shfl_xor(v1,off); v2+=__shfl_xor(v2,off);
      v3+=__shfl_xor(v3,off); v4+=__shfl_xor(v4,off); v5+=__shfl_xor(v5,off);
    }
    if (lane==0){
      redf[wave][0]=v0; redf[wave][1]=v1; redf[wave][2]=v2;
      redf[wave][3]=v3; redf[wave][4]=v4; redf[wave][5]=v5;
    }
  }
  __syncthreads();
  if (tid == 0){
    int c0=0,c1=0,c2=0;
    float v[6]={0,0,0,0,0,0};
    for (int w2=0; w2<16; w2++){
      c0+=redi[w2][0]; c1+=redi[w2][1]; c2+=redi[w2][2];
      for (int j=0;j<6;j++) v[j]+=redf[w2][j];
    }
    cns[0]=c0; cns[1]=c1; cns[2]=c2;
    for (int j=0;j<6;j++) tot6[j]=v[j];
  }
  __syncthreads();

  // ---- 3) pair partials ----
  {
    float p=0,n=0,s2=0,d=0;
    for (int s = tid; s < nblk; s += 1024){
      float4 a = *(const float4*)(pairPart + s*4);
      p+=a.x; n+=a.y; s2+=a.z; d+=a.w;
    }
    #pragma unroll
    for (int off=32; off; off>>=1){
      p+=__shfl_xor(p,off); n+=__shfl_xor(n,off);
      s2+=__shfl_xor(s2,off); d+=__shfl_xor(d,off);
    }
    if (lane==0){ redf[wave][0]=p; redf[wave][1]=n; redf[wave][2]=s2; redf[wave][3]=d; }
  }
  __syncthreads();
  if (tid == 0){
    float a=0,b=0,c=0,e=0;
    for (int w2=0; w2<16; w2++){ a+=redf[w2][0]; b+=redf[w2][1]; c+=redf[w2][2]; e+=redf[w2][3]; }
    ptot[0]=a; ptot[1]=b; ptot[2]=c; ptot[3]=e;
  }
  __syncthreads();

  int n0=cns[0], n1=cns[1], n2=cns[2];

  // ---- 4) triplet ----
  float tsum = 0.f, tcnt = 0.f;
  for (int i = tid; i < B; i += 1024){
    int t = targets[i];
    int nt = (t==0)?n0:((t==1)?n1:n2);
    if (nt - 1 > 0 && B - nt > 0){
      float mn = unmapf(rowMinU[i]);
      float mx = unmapf(rowMaxU[i]);
      float hp = sqrtf(fmaxf(2.f - 2.f*mn, 0.f));
      float hn = sqrtf(fmaxf(2.f - 2.f*mx, 0.f));
      float margin = 1.5f * ((t==1) ? 2.5f : 1.f);
      float tl = fmaxf(hp - hn + margin, 0.f);
      tsum += tl; tcnt += 1.f;
    }
  }
  #pragma unroll
  for (int off=32; off; off>>=1){ tsum += __shfl_xor(tsum, off); tcnt += __shfl_xor(tcnt, off); }
  if (lane==0){ redf[wave][6]=tsum; redf[wave][7]=tcnt; }
  __syncthreads();

  if (tid==0){
    float ts=0, tn=0;
    for (int w2=0; w2<16; w2++){ ts+=redf[w2][6]; tn+=redf[w2][7]; }
    float triplet = (tn > 0.f) ? ts / fmaxf(tn, 1.f) : 0.f;
    float pos=ptot[0], neg=ptot[1], semi=ptot[2], diag=ptot[3];
    float Bf = (float)B;
    float focal = tot6[0] / Bf;
    float ce = tot6[1] / tot6[2];
    float boundary = tot6[3] / (Bf + 1e-8f);
    float contrastive = (pos + neg + 4.f*semi) / (Bf*Bf + 1e-8f);
    long long npl = ((long long)n0*(n0-1) + (long long)n1*(n1-1) + (long long)n2*(n2-1))/2;
    float qsum = (pos - diag) * 0.5f;
    float q = qsum / (float)(npl > 0 ? npl : 1);
    if (n2 > 0) q *= (1.f + 2.5f * ((float)n2 / Bf));
    float quality = (npl > 0) ? q : 0.f;
    int ep = epoch_p[0];
    float er = (float)ep / 25.f;
    float ann = fminf(1.f, er*er);
    float evidential = tot6[4]/Bf + ann*0.2f*tot6[5]/Bf;
    float total = 0.4f*focal + 0.3f*ce + 0.15f*boundary
                + 0.1f*contrastive + 0.1f*triplet + 0.1f*quality + 0.1f*evidential;
    out[0] = total;
  }
}

extern "C" void kernel_launch(void* const* d_in, const int* in_sizes, int n_in,
                              void* d_out, int out_size, void* d_ws, size_t ws_size,
                              hipStream_t stream){
  const float* logits   = (const float*)d_in[0];
  const int*   targets  = (const int*)d_in[1];
  const float* features = (const float*)d_in[2];
  const float* alpha    = (const float*)d_in[3];
  const int*   epoch    = (const int*)d_in[4];
  const float* fa       = (const float*)d_in[5];
  const float* cw       = (const float*)d_in[6];
  int B = in_sizes[1];
  int D = in_sizes[2] / B;
  int nprep = B/4;                 // k_prep blocks == psum slots
  int T  = B / 64;
  int nblk = T*(T+1)/2;            // triangular: by <= bx
  int nper = (nblk + 7) / 8;       // tiles per XCD arc
  int grid = nper * 8;

  char* ws = (char*)d_ws;
  float*    psum     = (float*)(ws);                          // nprep*8 f32 (32KB)
  float*    pairPart = (float*)(ws + 65536);                  // nblk*4 f32 (~33KB)
  unsigned* rowMinU  = (unsigned*)(ws + 131072);              // B u32
  unsigned* rowMaxU  = (unsigned*)(ws + 131072 + (size_t)B*4);
  __bf16*   fb2      = (__bf16*)(ws + 131072 + (size_t)B*8);  // B*D bf16 tiled

  k_prep <<<nprep, 256, 0, stream>>>(features, fb2, logits, targets, alpha, fa, cw,
                                     B, D, psum, rowMinU, rowMaxU);
  k_pairs<<<grid, 64, 0, stream>>>(fb2, targets, B, D, pairPart, rowMinU, rowMaxU,
                                   nblk, nper);
  k_final<<<1, 1024, 0, stream>>>(targets, epoch, B, nprep, nblk, pairPart, psum,
                                  rowMinU, rowMaxU, (float*)d_out);
}